// Round 8
// baseline (3333.343 us; speedup 1.0000x reference)
//
#include <hip/hip_runtime.h>
#include <hip/hip_fp16.h>

// GRUPK R8: MFMA recurrence, barrier-drain fix.
// R7 evidence: recur 134us = 5040 cy/step vs ~1100 cy of work; MfmaUtil 7.3%,
// VALUBusy 10% -> latency-bound. Root cause: __syncthreads emits
// s_waitcnt vmcnt(0) before s_barrier (the m97 drain), so the per-step xg
// prefetch + hout store pay full L2/L3 latency inside every step.
// R8: (1) in-loop barrier = raw lgkmcnt(0)+s_barrier (LDS-only ordering; the
//     barrier only protects shA) -> global loads/stores stay in flight;
// (2) nonlin/scatter/prefetch masked to lanes<32 (q>=2 was duplicate garbage):
//     halves trans-pipe + xg traffic, scatter becomes 2-way (free) conflicts;
// (3) phaseB1 128 blocks x 4 m-pairs (Wi1frag L2 re-reads 201->50MB).
//
// ws layout (bytes): unchanged from R7 (60948480 total).

#define SCH 64
#define NCH 16

typedef _Float16 half8 __attribute__((ext_vector_type(8)));
typedef _Float16 half4_t __attribute__((ext_vector_type(4)));
typedef float f32x4 __attribute__((ext_vector_type(4)));

__device__ __forceinline__ float rcp_(float x) {
#if __has_builtin(__builtin_amdgcn_rcpf)
    return __builtin_amdgcn_rcpf(x);
#else
    return 1.f / x;
#endif
}
__device__ __forceinline__ float exp2_(float x) {
#if __has_builtin(__builtin_amdgcn_exp2f)
    return __builtin_amdgcn_exp2f(x);
#else
    return exp2f(x);
#endif
}
__device__ __forceinline__ float sigf(float v) {
    return rcp_(1.f + exp2_(v * -1.442695041f));
}
__device__ __forceinline__ float tanh_(float v) {
    return 1.f - 2.f * rcp_(1.f + exp2_(v * 2.885390082f));
}

// LDS-only barrier: drains DS ops, leaves vmcnt (global loads/stores) in flight.
__device__ __forceinline__ void lds_barrier() {
    __asm__ volatile("s_waitcnt lgkmcnt(0)" ::: "memory");
    __builtin_amdgcn_s_barrier();
}

// ---------- prep: W -> MFMA B-fragment layout [kt][nt][lane][8] f16 ----------
__global__ __launch_bounds__(256) void prep_kernel(
    const float* __restrict__ Whh0, const float* __restrict__ Whh1,
    const float* __restrict__ Wih1,
    _Float16* __restrict__ Wfrag0, _Float16* __restrict__ Wfrag1,
    _Float16* __restrict__ Wi1frag) {
    int tid = blockIdx.x * 256 + threadIdx.x;     // 3 * 24576 = 73728
    int mat = tid / 24576;
    int r   = tid % 24576;                        // = (kt*48 + nt)*64 + lane
    int kt   = r / 3072;
    int rem  = r % 3072;
    int nt   = rem >> 6;
    int lane = rem & 63;
    int n = nt * 16 + (lane & 15);
    int k = kt * 32 + (lane >> 4) * 8;
    const float* src = (mat == 0 ? Whh0 : (mat == 1 ? Whh1 : Wih1)) + n * 256 + k;
    _Float16* dst = (mat == 0 ? Wfrag0 : (mat == 1 ? Wfrag1 : Wi1frag)) + (size_t)r * 8;
#pragma unroll
    for (int j = 0; j < 8; j++) dst[j] = (_Float16)src[j];
}

// ---------- phaseB0: xg0t (lane-major layout) = [x|meta] @ Wih0^T + bih0 (+bhh0 r,z) ----------
__global__ __launch_bounds__(256) void phaseB0_kernel(
    const float* __restrict__ x, const float* __restrict__ meta,
    const float* __restrict__ Wih0, const float* __restrict__ bih0,
    const float* __restrict__ bhh0, _Float16* __restrict__ xg0t, int chunk) {
    __shared__ float Wb[6144];
    __shared__ float Bb[768];
    const int t = threadIdx.x;
    const int sq = blockIdx.x;    // 4 quarters of 16 steps
    const int blk = blockIdx.y;   // 32 batch-octets
    for (int i = t; i < 6144; i += 256) Wb[i] = Wih0[i];
    for (int i = t; i < 768; i += 256) Bb[i] = bih0[i] + (i < 512 ? bhh0[i] : 0.f);
    __syncthreads();
    const int w = t >> 5, l32 = t & 31;
    const int qc = l32 >> 4, lm = l32 & 15;

    float Wr[6][8], br[6];
#pragma unroll
    for (int g3 = 0; g3 < 3; g3++)
#pragma unroll
        for (int tp = 0; tp < 2; tp++) {
            int n = g3 * 256 + 32 * w + 16 * tp + lm;
            int j6 = g3 * 2 + tp;
#pragma unroll
            for (int kk = 0; kk < 8; kk++) Wr[j6][kk] = Wb[n * 8 + kk];
            br[j6] = Bb[n];
        }
    const int b0 = blk * 8 + qc * 4;
    float4 mv[4];
#pragma unroll
    for (int r = 0; r < 4; r++) mv[r] = *(const float4*)(meta + (b0 + r) * 4);

    for (int sl = 0; sl < 16; sl++) {
        int s_local = sq * 16 + sl;
        int s = chunk * SCH + s_local;
        float4 xv[4];
#pragma unroll
        for (int r = 0; r < 4; r++)
            xv[r] = *(const float4*)(x + ((size_t)(b0 + r) * 1024 + s) * 4);
        half8 o[3];
#pragma unroll
        for (int g3 = 0; g3 < 3; g3++)
#pragma unroll
            for (int tp = 0; tp < 2; tp++) {
                int j6 = g3 * 2 + tp;
#pragma unroll
                for (int r = 0; r < 4; r++) {
                    float v = br[j6]
                        + xv[r].x * Wr[j6][0] + xv[r].y * Wr[j6][1]
                        + xv[r].z * Wr[j6][2] + xv[r].w * Wr[j6][3]
                        + mv[r].x * Wr[j6][4] + mv[r].y * Wr[j6][5]
                        + mv[r].z * Wr[j6][6] + mv[r].w * Wr[j6][7];
                    o[g3][tp * 4 + r] = (_Float16)v;
                }
            }
        _Float16* dst = xg0t + (((size_t)(s_local * 32 + blk) * 8 + w) * 32 + l32) * 24;
        *(half8*)(dst)      = o[0];
        *(half8*)(dst + 8)  = o[1];
        *(half8*)(dst + 16) = o[2];
    }
}

// ---------- phaseB1: xg1t (lane-major) = h0 @ Wih1^T + bih1 (+bhh1 r,z) ----------
__global__ __launch_bounds__(256) void phaseB1_kernel(
    const _Float16* __restrict__ houtfrag, const _Float16* __restrict__ Wi1frag,
    const float* __restrict__ bih1, const float* __restrict__ bhh1,
    _Float16* __restrict__ xg1t) {
    const int tid = threadIdx.x, wv = tid >> 6, lane = tid & 63;
    const int q = lane >> 4, lm = lane & 15;
    const int asel = (lane >> 3) & 1;            // producer block parity for A rows
    const int cidx = (lane >> 4) * 8 + (lane & 7);

    float bias[12];
#pragma unroll
    for (int j = 0; j < 12; j++) {
        int n = (wv * 12 + j) * 16 + lm;
        bias[j] = bih1[n] + (n < 512 ? bhh1[n] : 0.f);
    }
    for (int mm = 0; mm < 4; mm++) {             // 128 blocks x 4 m-pairs
        int t16 = (blockIdx.x * 4 + mm) * 2;
        f32x4 acc[2][12] = {};
#pragma unroll
        for (int kt = 0; kt < 8; kt++) {
            half8 af[2], bf[12];
#pragma unroll
            for (int i = 0; i < 2; i++) {
                int tt = t16 + i, s = tt >> 4, bt = tt & 15;
                af[i] = *(const half8*)(houtfrag +
                    (((size_t)(s * 32 + bt * 2 + asel) * 8 + kt) * 32 + cidx) * 8);
            }
#pragma unroll
            for (int j = 0; j < 12; j++)
                bf[j] = *(const half8*)(Wi1frag + (size_t)((kt * 48 + wv * 12 + j) * 64 + lane) * 8);
#pragma unroll
            for (int i = 0; i < 2; i++)
#pragma unroll
                for (int j = 0; j < 12; j++)
                    acc[i][j] = __builtin_amdgcn_mfma_f32_16x16x32_f16(af[i], bf[j], acc[i][j], 0, 0, 0);
        }
#pragma unroll
        for (int i = 0; i < 2; i++) {
            int tt = t16 + i, s = tt >> 4, bt = tt & 15;
            int blk = bt * 2 + (q >> 1), qc = q & 1;
#pragma unroll
            for (int j = 0; j < 12; j++) {
                int n = (wv * 12 + j) * 16 + lm;
                int g3 = n >> 8, nn = n & 255;
                int wc = nn >> 5, tp = (nn >> 4) & 1, lmc = nn & 15;
                half4_t v;
#pragma unroll
                for (int r = 0; r < 4; r++) v[r] = (_Float16)(acc[i][j][r] + bias[j]);
                *(half4_t*)(xg1t + (((size_t)(s * 32 + blk) * 8 + wc) * 32 + qc * 16 + lmc) * 24
                                 + g3 * 8 + tp * 4) = v;
            }
        }
    }
}

// ---------- fused recurrence: blocks 0-31 = L0 chunk c, 32-63 = L1 chunk c-1 ----------
__global__
__attribute__((amdgpu_flat_work_group_size(512, 512), amdgpu_waves_per_eu(2, 2)))
void recur_kernel(
    const _Float16* __restrict__ Wfrag0, const float* __restrict__ bhh0,
    const _Float16* __restrict__ xg0t, float* __restrict__ hst0,
    const _Float16* __restrict__ Wfrag1, const float* __restrict__ bhh1,
    const _Float16* __restrict__ xg1t, float* __restrict__ hst1,
    _Float16* __restrict__ houtfrag, const float* __restrict__ fcW,
    const float* __restrict__ fcb, float* __restrict__ out, int c) {
    const int role = blockIdx.x >> 5;
    if (role == 0 && c == NCH) return;
    if (role == 1 && c == 0) return;
    const int cc = role ? c - 1 : c;
    const _Float16* Wfrag = role ? Wfrag1 : Wfrag0;
    const float* bhh      = role ? bhh1 : bhh0;
    const _Float16* xgt   = role ? xg1t : xg0t;
    float* hstate         = role ? hst1 : hst0;
    const bool doHout = (role == 0);
    const bool doFC   = (role == 1) && (cc == NCH - 1);

    __shared__ _Float16 shA[2 * 4160];   // double-buffered h, A-frag layout [kt][64 rows][8] (+pad)
    __shared__ float shred[2048];
    const int tid = threadIdx.x, w = tid >> 6, lane = tid & 63;
    const int q = lane >> 4, lm = lane & 15;
    const int blk = blockIdx.x & 31;

    int nt[6];
    nt[0] = 2 * w;      nt[1] = 2 * w + 1;
    nt[2] = 16 + 2 * w; nt[3] = 17 + 2 * w;
    nt[4] = 32 + 2 * w; nt[5] = 33 + 2 * w;

    // resident weights: 48 B-fragments = 192 regs (MFMA-native AGPR operands)
    half8 Bf[48];
#pragma unroll
    for (int kt = 0; kt < 8; kt++)
#pragma unroll
        for (int t = 0; t < 6; t++)
            Bf[kt * 6 + t] = *(const half8*)(Wfrag + (size_t)((kt * 48 + nt[t]) * 64 + lane) * 8);

    // only the n-gate bhh stays (r,z folded into xg biases)
    const float bbn0 = bhh[512 + 32 * w + lm];
    const float bbn1 = bhh[512 + 32 * w + 16 + lm];

    // h state: lane owns (m=4q+r, j=32w+16tp+lm); valid for q<2 (M=8)
    float hreg[2][4];
    if (cc == 0) {
#pragma unroll
        for (int tp = 0; tp < 2; tp++)
#pragma unroll
            for (int r = 0; r < 4; r++) hreg[tp][r] = 0.f;
    } else {
        f32x4 v0 = *(const f32x4*)(hstate + (size_t)((blk * 8 + w) * 64 + lane) * 8);
        f32x4 v1 = *(const f32x4*)(hstate + (size_t)((blk * 8 + w) * 64 + lane) * 8 + 4);
#pragma unroll
        for (int r = 0; r < 4; r++) { hreg[0][r] = v0[r]; hreg[1][r] = v1[r]; }
    }

    // seed shA[0] (A-frag scatter; q>=2 lanes fill garbage rows 8..15 harmlessly)
#pragma unroll
    for (int tp = 0; tp < 2; tp++)
#pragma unroll
        for (int r = 0; r < 4; r++)
            shA[w * 520 + ((2 * tp + (lm >> 3)) * 16 + 4 * q + r) * 8 + (lm & 7)] =
                (_Float16)hreg[tp][r];

    // xg: per-lane 48B contiguous; only lanes<32 consume it
    const _Float16* xbase = xgt + ((size_t)blk * 8 + w) * 768 + (lane & 31) * 24;
    half8 xc0, xc1, xc2;
    if (lane < 32) {
        xc0 = *(const half8*)(xbase);
        xc1 = *(const half8*)(xbase + 8);
        xc2 = *(const half8*)(xbase + 16);
    }

    __syncthreads();

    for (int s = 0; s < SCH; s++) {
        const int p = s & 1;
        f32x4 acc[6] = {};
#pragma unroll
        for (int kt = 0; kt < 8; kt++) {
            half8 af = *(const half8*)(shA + p * 4160 + kt * 520 + lane * 8);
#pragma unroll
            for (int t = 0; t < 6; t++)
                acc[t] = __builtin_amdgcn_mfma_f32_16x16x32_f16(af, Bf[kt * 6 + t], acc[t], 0, 0, 0);
        }

        if (lane < 32) {
#pragma unroll
            for (int tp = 0; tp < 2; tp++) {
                const float bbn = tp ? bbn1 : bbn0;
#pragma unroll
                for (int r = 0; r < 4; r++) {
                    float rr = sigf((float)xc0[tp * 4 + r] + acc[tp][r]);
                    float zz = sigf((float)xc1[tp * 4 + r] + acc[2 + tp][r]);
                    float nn = tanh_((float)xc2[tp * 4 + r] + rr * (acc[4 + tp][r] + bbn));
                    float h = nn + zz * (hreg[tp][r] - nn);
                    hreg[tp][r] = h;
                    shA[(p ^ 1) * 4160 + w * 520 +
                        ((2 * tp + (lm >> 3)) * 16 + 4 * q + r) * 8 + (lm & 7)] = (_Float16)h;
                }
            }
            // prefetch next step's xg; stays in flight across the lds_barrier
            {
                int snext = (s + 1 < SCH) ? s + 1 : s;
                const _Float16* xp2 = xbase + (size_t)snext * 196608;
                xc0 = *(const half8*)(xp2);
                xc1 = *(const half8*)(xp2 + 8);
                xc2 = *(const half8*)(xp2 + 16);
            }
        }

        if (doHout && (lane & 8) == 0) {   // own-wave region read (lgkm-ordered) + store
            half8 v = *(const half8*)(shA + (p ^ 1) * 4160 + w * 520 + lane * 8);
            *(half8*)(houtfrag +
                (((size_t)(s * 32 + blk) * 8 + w) * 32 + ((lane >> 4) * 8 + (lane & 7))) * 8) = v;
        }

        lds_barrier();   // drains DS only; xg prefetch + hout store stay outstanding
    }

    // persist h state
    {
        f32x4 v0, v1;
#pragma unroll
        for (int r = 0; r < 4; r++) { v0[r] = hreg[0][r]; v1[r] = hreg[1][r]; }
        *(f32x4*)(hstate + (size_t)((blk * 8 + w) * 64 + lane) * 8) = v0;
        *(f32x4*)(hstate + (size_t)((blk * 8 + w) * 64 + lane) * 8 + 4) = v1;
    }

    if (doFC) {   // out[b] = h2 . fcW + fcb for this block's 8 batches
        float fw0 = fcW[32 * w + lm], fw1 = fcW[32 * w + 16 + lm];
        f32x4 pv;
#pragma unroll
        for (int r = 0; r < 4; r++) pv[r] = hreg[0][r] * fw0 + hreg[1][r] * fw1;
        *(f32x4*)(shred + (size_t)(w * 64 + lane) * 4) = pv;
        __syncthreads();
        if (tid < 8) {
            int qq = tid >> 2, rr2 = tid & 3;
            float a = fcb[0];
            for (int ww = 0; ww < 8; ww++)
                for (int l2 = 0; l2 < 16; l2++)
                    a += shred[(ww * 64 + qq * 16 + l2) * 4 + rr2];
            out[blk * 8 + tid] = a;
        }
    }
}

extern "C" void kernel_launch(void* const* d_in, const int* in_sizes, int n_in,
                              void* d_out, int out_size, void* d_ws, size_t ws_size,
                              hipStream_t stream) {
    const float* x    = (const float*)d_in[0];
    const float* meta = (const float*)d_in[1];
    const float* Wih0 = (const float*)d_in[2];
    const float* Whh0 = (const float*)d_in[3];
    const float* bih0 = (const float*)d_in[4];
    const float* bhh0 = (const float*)d_in[5];
    const float* Wih1 = (const float*)d_in[6];
    const float* Whh1 = (const float*)d_in[7];
    const float* bih1 = (const float*)d_in[8];
    const float* bhh1 = (const float*)d_in[9];
    const float* fcW  = (const float*)d_in[10];
    const float* fcb  = (const float*)d_in[11];
    float* out = (float*)d_out;

    char* ws = (char*)d_ws;
    _Float16* Wfrag0   = (_Float16*)(ws + 0);
    _Float16* Wfrag1   = (_Float16*)(ws + 393216);
    _Float16* Wi1frag  = (_Float16*)(ws + 786432);
    float*    hst0     = (float*)(ws + 1179648);
    float*    hst1     = (float*)(ws + 1703936);
    _Float16* houtfrag = (_Float16*)(ws + 2228224);
    _Float16* xg0t     = (_Float16*)(ws + 10616832);
    _Float16* xg1t     = (_Float16*)(ws + 35782656);

    prep_kernel<<<288, 256, 0, stream>>>(Whh0, Whh1, Wih1, Wfrag0, Wfrag1, Wi1frag);

    for (int c = 0; c <= NCH; c++) {
        if (c < NCH)
            phaseB0_kernel<<<dim3(4, 32), 256, 0, stream>>>(x, meta, Wih0, bih0, bhh0, xg0t, c);
        recur_kernel<<<64, 512, 0, stream>>>(Wfrag0, bhh0, xg0t, hst0,
                                             Wfrag1, bhh1, xg1t, hst1,
                                             houtfrag, fcW, fcb, out, c);
        if (c < NCH)
            phaseB1_kernel<<<128, 256, 0, stream>>>(houtfrag, Wi1frag, bih1, bhh1, xg1t);
    }
}

// Round 9
// 2947.668 us; speedup vs baseline: 1.1308x; 1.1308x over previous
//
#include <hip/hip_runtime.h>
#include <hip/hip_fp16.h>

// GRUPK R9: MFMA recurrence, register-demand fix.
// R8 accounting: recur 4650 cy/step; MFMA 465 + VALU 510 busy -> ~3500 cy stall.
// Theory: per-wave demand ~264 regs (Bf 192 + acc 24 + xc 12 + hreg 8 + ~28
// addressing) > 256 budget -> compiler remats Bf frags from L2 in the K-loop
// every step (~15KB/wave/step at ~56 B/cy/CU L2 ~= the missing ~2000-3000 cy).
// R9: (1) step loop unrolled x2 -> double-buffer side is compile-time; ALL LDS
//     addresses = 1 base VGPR + immediate offsets; 1 xg pointer (was 6) and
//     1 hout pointer, advanced by constants. Demand ~245 < 256.
// (2) no lane<32 branch on loads/nonlin (dup lanes are free; simpler liveness).
// (3) phaseB1 back to 512 blocks (R8's 128-block version cost ~300us).
//
// ws layout (bytes): unchanged from R7 (60948480 total).

#define SCH 64
#define NCH 16

typedef _Float16 half8 __attribute__((ext_vector_type(8)));
typedef _Float16 half4_t __attribute__((ext_vector_type(4)));
typedef float f32x4 __attribute__((ext_vector_type(4)));

__device__ __forceinline__ float rcp_(float x) {
#if __has_builtin(__builtin_amdgcn_rcpf)
    return __builtin_amdgcn_rcpf(x);
#else
    return 1.f / x;
#endif
}
__device__ __forceinline__ float exp2_(float x) {
#if __has_builtin(__builtin_amdgcn_exp2f)
    return __builtin_amdgcn_exp2f(x);
#else
    return exp2f(x);
#endif
}
__device__ __forceinline__ float sigf(float v) {
    return rcp_(1.f + exp2_(v * -1.442695041f));
}
__device__ __forceinline__ float tanh_(float v) {
    return 1.f - 2.f * rcp_(1.f + exp2_(v * 2.885390082f));
}

// LDS-only barrier: drains DS ops, leaves vmcnt (global loads/stores) in flight.
__device__ __forceinline__ void lds_barrier() {
    __asm__ volatile("s_waitcnt lgkmcnt(0)" ::: "memory");
    __builtin_amdgcn_s_barrier();
}

// ---------- prep: W -> MFMA B-fragment layout [kt][nt][lane][8] f16 ----------
__global__ __launch_bounds__(256) void prep_kernel(
    const float* __restrict__ Whh0, const float* __restrict__ Whh1,
    const float* __restrict__ Wih1,
    _Float16* __restrict__ Wfrag0, _Float16* __restrict__ Wfrag1,
    _Float16* __restrict__ Wi1frag) {
    int tid = blockIdx.x * 256 + threadIdx.x;     // 3 * 24576 = 73728
    int mat = tid / 24576;
    int r   = tid % 24576;                        // = (kt*48 + nt)*64 + lane
    int kt   = r / 3072;
    int rem  = r % 3072;
    int nt   = rem >> 6;
    int lane = rem & 63;
    int n = nt * 16 + (lane & 15);
    int k = kt * 32 + (lane >> 4) * 8;
    const float* src = (mat == 0 ? Whh0 : (mat == 1 ? Whh1 : Wih1)) + n * 256 + k;
    _Float16* dst = (mat == 0 ? Wfrag0 : (mat == 1 ? Wfrag1 : Wi1frag)) + (size_t)r * 8;
#pragma unroll
    for (int j = 0; j < 8; j++) dst[j] = (_Float16)src[j];
}

// ---------- phaseB0: xg0t (lane-major layout) = [x|meta] @ Wih0^T + bih0 (+bhh0 r,z) ----------
__global__ __launch_bounds__(256) void phaseB0_kernel(
    const float* __restrict__ x, const float* __restrict__ meta,
    const float* __restrict__ Wih0, const float* __restrict__ bih0,
    const float* __restrict__ bhh0, _Float16* __restrict__ xg0t, int chunk) {
    __shared__ float Wb[6144];
    __shared__ float Bb[768];
    const int t = threadIdx.x;
    const int sq = blockIdx.x;    // 4 quarters of 16 steps
    const int blk = blockIdx.y;   // 32 batch-octets
    for (int i = t; i < 6144; i += 256) Wb[i] = Wih0[i];
    for (int i = t; i < 768; i += 256) Bb[i] = bih0[i] + (i < 512 ? bhh0[i] : 0.f);
    __syncthreads();
    const int w = t >> 5, l32 = t & 31;
    const int qc = l32 >> 4, lm = l32 & 15;

    float Wr[6][8], br[6];
#pragma unroll
    for (int g3 = 0; g3 < 3; g3++)
#pragma unroll
        for (int tp = 0; tp < 2; tp++) {
            int n = g3 * 256 + 32 * w + 16 * tp + lm;
            int j6 = g3 * 2 + tp;
#pragma unroll
            for (int kk = 0; kk < 8; kk++) Wr[j6][kk] = Wb[n * 8 + kk];
            br[j6] = Bb[n];
        }
    const int b0 = blk * 8 + qc * 4;
    float4 mv[4];
#pragma unroll
    for (int r = 0; r < 4; r++) mv[r] = *(const float4*)(meta + (b0 + r) * 4);

    for (int sl = 0; sl < 16; sl++) {
        int s_local = sq * 16 + sl;
        int s = chunk * SCH + s_local;
        float4 xv[4];
#pragma unroll
        for (int r = 0; r < 4; r++)
            xv[r] = *(const float4*)(x + ((size_t)(b0 + r) * 1024 + s) * 4);
        half8 o[3];
#pragma unroll
        for (int g3 = 0; g3 < 3; g3++)
#pragma unroll
            for (int tp = 0; tp < 2; tp++) {
                int j6 = g3 * 2 + tp;
#pragma unroll
                for (int r = 0; r < 4; r++) {
                    float v = br[j6]
                        + xv[r].x * Wr[j6][0] + xv[r].y * Wr[j6][1]
                        + xv[r].z * Wr[j6][2] + xv[r].w * Wr[j6][3]
                        + mv[r].x * Wr[j6][4] + mv[r].y * Wr[j6][5]
                        + mv[r].z * Wr[j6][6] + mv[r].w * Wr[j6][7];
                    o[g3][tp * 4 + r] = (_Float16)v;
                }
            }
        _Float16* dst = xg0t + (((size_t)(s_local * 32 + blk) * 8 + w) * 32 + l32) * 24;
        *(half8*)(dst)      = o[0];
        *(half8*)(dst + 8)  = o[1];
        *(half8*)(dst + 16) = o[2];
    }
}

// ---------- phaseB1: xg1t (lane-major) = h0 @ Wih1^T + bih1 (+bhh1 r,z) ----------
__global__ __launch_bounds__(256) void phaseB1_kernel(
    const _Float16* __restrict__ houtfrag, const _Float16* __restrict__ Wi1frag,
    const float* __restrict__ bih1, const float* __restrict__ bhh1,
    _Float16* __restrict__ xg1t) {
    const int tid = threadIdx.x, wv = tid >> 6, lane = tid & 63;
    const int q = lane >> 4, lm = lane & 15;
    const int t16 = blockIdx.x * 2;              // 512 blocks x 2 m-tiles
    const int asel = (lane >> 3) & 1;            // producer block parity for A rows
    const int cidx = (lane >> 4) * 8 + (lane & 7);

    float bias[12];
#pragma unroll
    for (int j = 0; j < 12; j++) {
        int n = (wv * 12 + j) * 16 + lm;
        bias[j] = bih1[n] + (n < 512 ? bhh1[n] : 0.f);
    }
    f32x4 acc[2][12] = {};
#pragma unroll
    for (int kt = 0; kt < 8; kt++) {
        half8 af[2], bf[12];
#pragma unroll
        for (int i = 0; i < 2; i++) {
            int tt = t16 + i, s = tt >> 4, bt = tt & 15;
            af[i] = *(const half8*)(houtfrag +
                (((size_t)(s * 32 + bt * 2 + asel) * 8 + kt) * 32 + cidx) * 8);
        }
#pragma unroll
        for (int j = 0; j < 12; j++)
            bf[j] = *(const half8*)(Wi1frag + (size_t)((kt * 48 + wv * 12 + j) * 64 + lane) * 8);
#pragma unroll
        for (int i = 0; i < 2; i++)
#pragma unroll
            for (int j = 0; j < 12; j++)
                acc[i][j] = __builtin_amdgcn_mfma_f32_16x16x32_f16(af[i], bf[j], acc[i][j], 0, 0, 0);
    }
#pragma unroll
    for (int i = 0; i < 2; i++) {
        int tt = t16 + i, s = tt >> 4, bt = tt & 15;
        int blk = bt * 2 + (q >> 1), qc = q & 1;
#pragma unroll
        for (int j = 0; j < 12; j++) {
            int n = (wv * 12 + j) * 16 + lm;
            int g3 = n >> 8, nn = n & 255;
            int wc = nn >> 5, tp = (nn >> 4) & 1, lmc = nn & 15;
            half4_t v;
#pragma unroll
            for (int r = 0; r < 4; r++) v[r] = (_Float16)(acc[i][j][r] + bias[j]);
            *(half4_t*)(xg1t + (((size_t)(s * 32 + blk) * 8 + wc) * 32 + qc * 16 + lmc) * 24
                             + g3 * 8 + tp * 4) = v;
        }
    }
}

// ---------- fused recurrence: blocks 0-31 = L0 chunk c, 32-63 = L1 chunk c-1 ----------
__global__
__attribute__((amdgpu_flat_work_group_size(512, 512), amdgpu_waves_per_eu(2, 2)))
void recur_kernel(
    const _Float16* __restrict__ Wfrag0, const float* __restrict__ bhh0,
    const _Float16* __restrict__ xg0t, float* __restrict__ hst0,
    const _Float16* __restrict__ Wfrag1, const float* __restrict__ bhh1,
    const _Float16* __restrict__ xg1t, float* __restrict__ hst1,
    _Float16* __restrict__ houtfrag, const float* __restrict__ fcW,
    const float* __restrict__ fcb, float* __restrict__ out, int c) {
    const int role = blockIdx.x >> 5;
    if (role == 0 && c == NCH) return;
    if (role == 1 && c == 0) return;
    const int cc = role ? c - 1 : c;
    const _Float16* Wfrag = role ? Wfrag1 : Wfrag0;
    const float* bhh      = role ? bhh1 : bhh0;
    const _Float16* xgt   = role ? xg1t : xg0t;
    float* hstate         = role ? hst1 : hst0;
    const bool doHout = (role == 0);
    const bool doFC   = (role == 1) && (cc == NCH - 1);

    __shared__ _Float16 shA[2 * 4160];   // double-buffered h, A-frag layout [kt][rows][8] (+pad)
    __shared__ float shred[2048];
    const int tid = threadIdx.x, w = tid >> 6, lane = tid & 63;
    const int q = lane >> 4, lm = lane & 15;
    const int blk = blockIdx.x & 31;

    int nt[6];
    nt[0] = 2 * w;      nt[1] = 2 * w + 1;
    nt[2] = 16 + 2 * w; nt[3] = 17 + 2 * w;
    nt[4] = 32 + 2 * w; nt[5] = 33 + 2 * w;

    // resident weights: 48 B-fragments = 192 regs (MFMA-native AGPR operands)
    half8 Bf[48];
#pragma unroll
    for (int kt = 0; kt < 8; kt++)
#pragma unroll
        for (int t = 0; t < 6; t++)
            Bf[kt * 6 + t] = *(const half8*)(Wfrag + (size_t)((kt * 48 + nt[t]) * 64 + lane) * 8);

    // only the n-gate bhh stays (r,z folded into xg biases)
    const float bbn0 = bhh[512 + 32 * w + lm];
    const float bbn1 = bhh[512 + 32 * w + 16 + lm];

    // h state: lane owns (m=4q+r, j=32w+16tp+lm); lanes 32-63 mirror 0-31
    float hreg[2][4];
    if (cc == 0) {
#pragma unroll
        for (int tp = 0; tp < 2; tp++)
#pragma unroll
            for (int r = 0; r < 4; r++) hreg[tp][r] = 0.f;
    } else {
        f32x4 v0 = *(const f32x4*)(hstate + (size_t)((blk * 8 + w) * 64 + lane) * 8);
        f32x4 v1 = *(const f32x4*)(hstate + (size_t)((blk * 8 + w) * 64 + lane) * 8 + 4);
#pragma unroll
        for (int r = 0; r < 4; r++) { hreg[0][r] = v0[r]; hreg[1][r] = v1[r]; }
    }

    // --- lean addressing: one base per access pattern, all else immediate ---
    _Float16* const ard = shA + lane * 8;                                  // MFMA read
    _Float16* const awr = shA + w * 520 + (lm >> 3) * 128 + q * 32 + (lm & 7);  // scatter
    _Float16* const hrd = shA + w * 520 + lane * 8;                        // hout read
    // xg: per-lane 48B contiguous; lanes 32-63 duplicate lanes 0-31 (free)
    const _Float16* xp = xgt + ((size_t)blk * 8 + w) * 768 + (lane & 31) * 24;
    _Float16* hop = houtfrag + ((size_t)blk * 8 + w) * 256 +
                    ((lane >> 4) * 8 + (lane & 7)) * 8;

    // seed side 0
#pragma unroll
    for (int tp = 0; tp < 2; tp++)
#pragma unroll
        for (int r = 0; r < 4; r++)
            awr[tp * 256 + r * 8] = (_Float16)hreg[tp][r];

    half8 xc0 = *(const half8*)(xp);
    half8 xc1 = *(const half8*)(xp + 8);
    half8 xc2 = *(const half8*)(xp + 16);

    __syncthreads();

#define GRU_STEP(SIDE, SEXPR)                                                     \
    {                                                                             \
        const int s_ = (SEXPR);                                                   \
        f32x4 acc[6] = {};                                                        \
        _Pragma("unroll")                                                         \
        for (int kt = 0; kt < 8; kt++) {                                          \
            half8 af = *(const half8*)(ard + (SIDE) * 4160 + kt * 520);           \
            _Pragma("unroll")                                                     \
            for (int t = 0; t < 6; t++)                                           \
                acc[t] = __builtin_amdgcn_mfma_f32_16x16x32_f16(                  \
                    af, Bf[kt * 6 + t], acc[t], 0, 0, 0);                         \
        }                                                                         \
        _Pragma("unroll")                                                         \
        for (int tp = 0; tp < 2; tp++) {                                          \
            const float bbn = tp ? bbn1 : bbn0;                                   \
            _Pragma("unroll")                                                     \
            for (int r = 0; r < 4; r++) {                                         \
                float rr = sigf((float)xc0[tp * 4 + r] + acc[tp][r]);             \
                float zz = sigf((float)xc1[tp * 4 + r] + acc[2 + tp][r]);         \
                float nn = tanh_((float)xc2[tp * 4 + r] +                         \
                                 rr * (acc[4 + tp][r] + bbn));                    \
                float h = nn + zz * (hreg[tp][r] - nn);                           \
                hreg[tp][r] = h;                                                  \
                awr[(1 - (SIDE)) * 4160 + tp * 256 + r * 8] = (_Float16)h;        \
            }                                                                     \
        }                                                                         \
        if (s_ + 1 < SCH) xp += 196608;  /* clamp: last step re-reads itself */   \
        xc0 = *(const half8*)(xp);                                                \
        xc1 = *(const half8*)(xp + 8);                                            \
        xc2 = *(const half8*)(xp + 16);                                           \
        if (doHout && (lane & 8) == 0) {                                          \
            half8 v = *(const half8*)(hrd + (1 - (SIDE)) * 4160);                 \
            *(half8*)hop = v;                                                     \
        }                                                                         \
        hop += 65536;                                                             \
        lds_barrier();                                                            \
    }

    for (int s2 = 0; s2 < SCH; s2 += 2) {
        GRU_STEP(0, s2);
        GRU_STEP(1, s2 + 1);
    }
#undef GRU_STEP

    // persist h state
    {
        f32x4 v0, v1;
#pragma unroll
        for (int r = 0; r < 4; r++) { v0[r] = hreg[0][r]; v1[r] = hreg[1][r]; }
        *(f32x4*)(hstate + (size_t)((blk * 8 + w) * 64 + lane) * 8) = v0;
        *(f32x4*)(hstate + (size_t)((blk * 8 + w) * 64 + lane) * 8 + 4) = v1;
    }

    if (doFC) {   // out[b] = h2 . fcW + fcb for this block's 8 batches
        float fw0 = fcW[32 * w + lm], fw1 = fcW[32 * w + 16 + lm];
        f32x4 pv;
#pragma unroll
        for (int r = 0; r < 4; r++) pv[r] = hreg[0][r] * fw0 + hreg[1][r] * fw1;
        *(f32x4*)(shred + (size_t)(w * 64 + lane) * 4) = pv;
        __syncthreads();
        if (tid < 8) {
            int qq = tid >> 2, rr2 = tid & 3;
            float a = fcb[0];
            for (int ww = 0; ww < 8; ww++)
                for (int l2 = 0; l2 < 16; l2++)
                    a += shred[(ww * 64 + qq * 16 + l2) * 4 + rr2];
            out[blk * 8 + tid] = a;
        }
    }
}

extern "C" void kernel_launch(void* const* d_in, const int* in_sizes, int n_in,
                              void* d_out, int out_size, void* d_ws, size_t ws_size,
                              hipStream_t stream) {
    const float* x    = (const float*)d_in[0];
    const float* meta = (const float*)d_in[1];
    const float* Wih0 = (const float*)d_in[2];
    const float* Whh0 = (const float*)d_in[3];
    const float* bih0 = (const float*)d_in[4];
    const float* bhh0 = (const float*)d_in[5];
    const float* Wih1 = (const float*)d_in[6];
    const float* Whh1 = (const float*)d_in[7];
    const float* bih1 = (const float*)d_in[8];
    const float* bhh1 = (const float*)d_in[9];
    const float* fcW  = (const float*)d_in[10];
    const float* fcb  = (const float*)d_in[11];
    float* out = (float*)d_out;

    char* ws = (char*)d_ws;
    _Float16* Wfrag0   = (_Float16*)(ws + 0);
    _Float16* Wfrag1   = (_Float16*)(ws + 393216);
    _Float16* Wi1frag  = (_Float16*)(ws + 786432);
    float*    hst0     = (float*)(ws + 1179648);
    float*    hst1     = (float*)(ws + 1703936);
    _Float16* houtfrag = (_Float16*)(ws + 2228224);
    _Float16* xg0t     = (_Float16*)(ws + 10616832);
    _Float16* xg1t     = (_Float16*)(ws + 35782656);

    prep_kernel<<<288, 256, 0, stream>>>(Whh0, Whh1, Wih1, Wfrag0, Wfrag1, Wi1frag);

    for (int c = 0; c <= NCH; c++) {
        if (c < NCH)
            phaseB0_kernel<<<dim3(4, 32), 256, 0, stream>>>(x, meta, Wih0, bih0, bhh0, xg0t, c);
        recur_kernel<<<64, 512, 0, stream>>>(Wfrag0, bhh0, xg0t, hst0,
                                             Wfrag1, bhh1, xg1t, hst1,
                                             houtfrag, fcW, fcb, out, c);
        if (c < NCH)
            phaseB1_kernel<<<512, 256, 0, stream>>>(houtfrag, Wi1frag, bih1, bhh1, xg1t);
    }
}

// Round 10
// 2280.937 us; speedup vs baseline: 1.4614x; 1.2923x over previous
//
#include <hip/hip_runtime.h>
#include <hip/hip_fp16.h>

// GRUPK R10: single fused pipelined kernel per chunk.
// R9 evidence: recur step = 4900 cy with only ~2400 cy accountable busy; no remat
// (FETCH = xg only); the rest is phase-lockstep latency at 2 waves/SIMD. Also
// ~740us of SERIAL phaseB0/B1 time between recur launches (64 CUs busy in recur,
// 0 in B-phases).
// R10: (1) fuse recur+B0+B1 into one 224-block kernel (64 recur / 32 B0 / 128 B1),
//     all blocks co-resident (1 block/CU at waves_per_eu(2,2)); software pipeline
//     across launches k=-1..33: L0(k), L1(k-2), B1(k-1), B0(k+1), double-buffered
//     xg0t/xg1t/hout, SCH=32 (ws unchanged 60.9MB).
// (2) recur LDS halved: shA holds only the 8 real rows (4KB/side); duplicate-lane
//     reads are same-address broadcast (free); scatter writes masked to lanes<32;
//     xg load at top-of-step (MFMA phase = latency slack); hout = lanes<32 b128.
//
// ws layout (bytes):
//   0         Wfrag0   393216      1179648  hst0 524288     2228224  hout0 4194304
//   393216    Wfrag1   393216      1703936  hst1 524288     6422528  hout1 4194304
//   786432    Wi1frag  393216
//   10616832  xg0a 12582912   23199744 xg0b   35782656 xg1a   48365568 xg1b
//   total 60948480

#define SCH 32
#define NCH 32

typedef _Float16 half8 __attribute__((ext_vector_type(8)));
typedef _Float16 half4_t __attribute__((ext_vector_type(4)));
typedef float f32x4 __attribute__((ext_vector_type(4)));

__device__ __forceinline__ float rcp_(float x) {
#if __has_builtin(__builtin_amdgcn_rcpf)
    return __builtin_amdgcn_rcpf(x);
#else
    return 1.f / x;
#endif
}
__device__ __forceinline__ float exp2_(float x) {
#if __has_builtin(__builtin_amdgcn_exp2f)
    return __builtin_amdgcn_exp2f(x);
#else
    return exp2f(x);
#endif
}
__device__ __forceinline__ float sigf(float v) {
    return rcp_(1.f + exp2_(v * -1.442695041f));
}
__device__ __forceinline__ float tanh_(float v) {
    return 1.f - 2.f * rcp_(1.f + exp2_(v * 2.885390082f));
}

// LDS-only barrier: drains DS ops, leaves vmcnt (global loads/stores) in flight.
__device__ __forceinline__ void lds_barrier() {
    __asm__ volatile("s_waitcnt lgkmcnt(0)" ::: "memory");
    __builtin_amdgcn_s_barrier();
}

// ---------- prep: W -> MFMA B-fragment layout [kt][nt][lane][8] f16 ----------
__global__ __launch_bounds__(256) void prep_kernel(
    const float* __restrict__ Whh0, const float* __restrict__ Whh1,
    const float* __restrict__ Wih1,
    _Float16* __restrict__ Wfrag0, _Float16* __restrict__ Wfrag1,
    _Float16* __restrict__ Wi1frag) {
    int tid = blockIdx.x * 256 + threadIdx.x;     // 3 * 24576 = 73728
    int mat = tid / 24576;
    int r   = tid % 24576;                        // = (kt*48 + nt)*64 + lane
    int kt   = r / 3072;
    int rem  = r % 3072;
    int nt   = rem >> 6;
    int lane = rem & 63;
    int n = nt * 16 + (lane & 15);
    int k = kt * 32 + (lane >> 4) * 8;
    const float* src = (mat == 0 ? Whh0 : (mat == 1 ? Whh1 : Wih1)) + n * 256 + k;
    _Float16* dst = (mat == 0 ? Wfrag0 : (mat == 1 ? Wfrag1 : Wi1frag)) + (size_t)r * 8;
#pragma unroll
    for (int j = 0; j < 8; j++) dst[j] = (_Float16)src[j];
}

// ---------- fused pipeline kernel ----------
// blocks [0,64): recurrence (role0 = L0 chunk k, role1 = L1 chunk k-2)
// blocks [64,96): B0 producing xg0t for chunk k+1
// blocks [96,224): B1 producing xg1t for chunk k-1 (from hout of chunk k-1)
__global__
__attribute__((amdgpu_flat_work_group_size(512, 512), amdgpu_waves_per_eu(2, 2)))
void mega_kernel(
    const float* __restrict__ x, const float* __restrict__ meta,
    const float* __restrict__ Wih0, const float* __restrict__ bih0,
    const float* __restrict__ bhh0,
    const _Float16* __restrict__ Wfrag0, const _Float16* __restrict__ Wfrag1,
    const _Float16* __restrict__ Wi1frag,
    const float* __restrict__ bih1, const float* __restrict__ bhh1,
    float* __restrict__ hst0, float* __restrict__ hst1,
    _Float16* __restrict__ hout0, _Float16* __restrict__ hout1,
    _Float16* __restrict__ xg0a, _Float16* __restrict__ xg0b,
    _Float16* __restrict__ xg1a, _Float16* __restrict__ xg1b,
    const float* __restrict__ fcW, const float* __restrict__ fcb,
    float* __restrict__ out, int k) {
    __shared__ __align__(16) char smem[27648];
    const int bid = blockIdx.x;
    const int tid = threadIdx.x;

    if (bid < 64) {
        // ================= recurrence =================
        const int role = bid >> 5;
        const int cc = role ? k - 2 : k;
        if (cc < 0 || cc >= NCH) return;
        const _Float16* Wfrag = role ? Wfrag1 : Wfrag0;
        const float* bhh      = role ? bhh1 : bhh0;
        const _Float16* xgt   = role ? ((cc & 1) ? xg1b : xg1a)
                                     : ((cc & 1) ? xg0b : xg0a);
        float* hstate         = role ? hst1 : hst0;
        _Float16* hof         = (cc & 1) ? hout1 : hout0;
        const bool doHout = (role == 0);
        const bool doFC   = (role == 1) && (cc == NCH - 1);

        _Float16* shA = (_Float16*)smem;   // 2 sides x [kt 8][kq 4][row 8][off 8] = 2x2048 halfs
        float* shred  = (float*)smem;      // FC alias (post-loop only)
        const int w = tid >> 6, lane = tid & 63;
        const int q = lane >> 4, lm = lane & 15;
        const int blk = bid & 31;

        int nt[6];
        nt[0] = 2 * w;      nt[1] = 2 * w + 1;
        nt[2] = 16 + 2 * w; nt[3] = 17 + 2 * w;
        nt[4] = 32 + 2 * w; nt[5] = 33 + 2 * w;

        half8 Bf[48];
#pragma unroll
        for (int kt = 0; kt < 8; kt++)
#pragma unroll
            for (int t = 0; t < 6; t++)
                Bf[kt * 6 + t] = *(const half8*)(Wfrag + (size_t)((kt * 48 + nt[t]) * 64 + lane) * 8);

        const float bbn0 = bhh[512 + 32 * w + lm];
        const float bbn1 = bhh[512 + 32 * w + 16 + lm];

        float hreg[2][4];
        if (cc == 0) {
#pragma unroll
            for (int tp = 0; tp < 2; tp++)
#pragma unroll
                for (int r = 0; r < 4; r++) hreg[tp][r] = 0.f;
        } else {
            f32x4 v0 = *(const f32x4*)(hstate + (size_t)((blk * 8 + w) * 64 + lane) * 8);
            f32x4 v1 = *(const f32x4*)(hstate + (size_t)((blk * 8 + w) * 64 + lane) * 8 + 4);
#pragma unroll
            for (int r = 0; r < 4; r++) { hreg[0][r] = v0[r]; hreg[1][r] = v1[r]; }
        }

        // LDS half-index bases. Element (kt,kq,row,off): kt*256 + kq*64 + row*8 + off.
        const int rdo = (lane >> 4) * 64 + (lane & 7) * 8;                 // read: row dup by lane&7
        const int wb  = w * 256 + (lm >> 3) * 64 + q * 32 + (lm & 7);      // scatter (lanes<32)

        if (lane < 32)
#pragma unroll
            for (int tp = 0; tp < 2; tp++)
#pragma unroll
                for (int r = 0; r < 4; r++)
                    shA[wb + tp * 128 + r * 8] = (_Float16)hreg[tp][r];

        const _Float16* xp = xgt + (size_t)(blk * 8 + w) * 768 + (lane & 31) * 24;
        _Float16* hop = hof + (size_t)(blk * 8 + w) * 256 + lane * 8;

        __syncthreads();

#define GRU_STEP(SIDE)                                                            \
    {                                                                             \
        half8 xc0 = *(const half8*)(xp);                                          \
        half8 xc1 = *(const half8*)(xp + 8);                                      \
        half8 xc2 = *(const half8*)(xp + 16);                                     \
        f32x4 acc[6] = {};                                                        \
        _Pragma("unroll")                                                         \
        for (int kt = 0; kt < 8; kt++) {                                          \
            half8 af = *(const half8*)(shA + (SIDE) * 2048 + kt * 256 + rdo);     \
            _Pragma("unroll")                                                     \
            for (int t = 0; t < 6; t++)                                           \
                acc[t] = __builtin_amdgcn_mfma_f32_16x16x32_f16(                  \
                    af, Bf[kt * 6 + t], acc[t], 0, 0, 0);                         \
        }                                                                         \
        _Pragma("unroll")                                                         \
        for (int tp = 0; tp < 2; tp++) {                                          \
            const float bbn = tp ? bbn1 : bbn0;                                   \
            _Pragma("unroll")                                                     \
            for (int r = 0; r < 4; r++) {                                         \
                float rr = sigf((float)xc0[tp * 4 + r] + acc[tp][r]);             \
                float zz = sigf((float)xc1[tp * 4 + r] + acc[2 + tp][r]);         \
                float nn = tanh_((float)xc2[tp * 4 + r] +                         \
                                 rr * (acc[4 + tp][r] + bbn));                    \
                hreg[tp][r] = nn + zz * (hreg[tp][r] - nn);                       \
            }                                                                     \
        }                                                                         \
        if (lane < 32) {                                                          \
            _Pragma("unroll")                                                     \
            for (int tp = 0; tp < 2; tp++)                                        \
                _Pragma("unroll")                                                 \
                for (int r = 0; r < 4; r++)                                       \
                    shA[((SIDE) ^ 1) * 2048 + wb + tp * 128 + r * 8] =            \
                        (_Float16)hreg[tp][r];                                    \
            if (doHout) {                                                         \
                half8 v = *(const half8*)(shA + ((SIDE) ^ 1) * 2048 +             \
                                          w * 256 + lane * 8);                    \
                *(half8*)hop = v;                                                 \
            }                                                                     \
        }                                                                         \
        hop += 65536;                                                             \
        xp += 196608;                                                             \
        lds_barrier();                                                            \
    }

        for (int s2 = 0; s2 < SCH; s2 += 2) {
            GRU_STEP(0);
            GRU_STEP(1);
        }
#undef GRU_STEP

        {
            f32x4 v0, v1;
#pragma unroll
            for (int r = 0; r < 4; r++) { v0[r] = hreg[0][r]; v1[r] = hreg[1][r]; }
            *(f32x4*)(hstate + (size_t)((blk * 8 + w) * 64 + lane) * 8) = v0;
            *(f32x4*)(hstate + (size_t)((blk * 8 + w) * 64 + lane) * 8 + 4) = v1;
        }

        if (doFC) {
            float fw0 = fcW[32 * w + lm], fw1 = fcW[32 * w + 16 + lm];
            f32x4 pv;
#pragma unroll
            for (int r = 0; r < 4; r++) pv[r] = hreg[0][r] * fw0 + hreg[1][r] * fw1;
            __syncthreads();   // shA reads done before shred alias write
            *(f32x4*)(shred + (size_t)(w * 64 + lane) * 4) = pv;
            __syncthreads();
            if (tid < 8) {
                int qq = tid >> 2, rr2 = tid & 3;
                float a = fcb[0];
                for (int ww = 0; ww < 8; ww++)
                    for (int l2 = 0; l2 < 16; l2++)
                        a += shred[(ww * 64 + qq * 16 + l2) * 4 + rr2];
                out[blk * 8 + tid] = a;
            }
        }
    } else if (bid < 96) {
        // ================= B0: xg0t(cb) = [x|meta] @ Wih0^T + bih0 (+bhh0 r,z) =================
        const int cb = k + 1;
        if (cb < 0 || cb >= NCH) return;
        _Float16* xg0 = (cb & 1) ? xg0b : xg0a;
        const int fb = bid - 64;                  // octet 0..31
        float* Wb = (float*)smem;                 // 6144 W + 768 bias
        for (int i = tid; i < 6912; i += 512)
            Wb[i] = (i < 6144) ? Wih0[i]
                               : (bih0[i - 6144] + ((i - 6144) < 512 ? bhh0[i - 6144] : 0.f));
        __syncthreads();
        const int sub = tid >> 8;                 // step-half 0..1
        const int t = tid & 255;
        const int w = t >> 5, l32 = t & 31;
        const int qc = l32 >> 4, lm = l32 & 15;

        float Wr[6][8], br[6];
#pragma unroll
        for (int g3 = 0; g3 < 3; g3++)
#pragma unroll
            for (int tp = 0; tp < 2; tp++) {
                int n = g3 * 256 + 32 * w + 16 * tp + lm;
                int j6 = g3 * 2 + tp;
#pragma unroll
                for (int kk = 0; kk < 8; kk++) Wr[j6][kk] = Wb[n * 8 + kk];
                br[j6] = Wb[6144 + n];
            }
        const int b0 = fb * 8 + qc * 4;
        float4 mv[4];
#pragma unroll
        for (int r = 0; r < 4; r++) mv[r] = *(const float4*)(meta + (b0 + r) * 4);

        for (int sl = 0; sl < 16; sl++) {
            int s_local = sub * 16 + sl;
            int s = cb * SCH + s_local;
            float4 xv[4];
#pragma unroll
            for (int r = 0; r < 4; r++)
                xv[r] = *(const float4*)(x + ((size_t)(b0 + r) * 1024 + s) * 4);
            half8 o[3];
#pragma unroll
            for (int g3 = 0; g3 < 3; g3++)
#pragma unroll
                for (int tp = 0; tp < 2; tp++) {
                    int j6 = g3 * 2 + tp;
#pragma unroll
                    for (int r = 0; r < 4; r++) {
                        float v = br[j6]
                            + xv[r].x * Wr[j6][0] + xv[r].y * Wr[j6][1]
                            + xv[r].z * Wr[j6][2] + xv[r].w * Wr[j6][3]
                            + mv[r].x * Wr[j6][4] + mv[r].y * Wr[j6][5]
                            + mv[r].z * Wr[j6][6] + mv[r].w * Wr[j6][7];
                        o[g3][tp * 4 + r] = (_Float16)v;
                    }
                }
            _Float16* dst = xg0 + (((size_t)(s_local * 32 + fb) * 8 + w) * 32 + l32) * 24;
            *(half8*)(dst)      = o[0];
            *(half8*)(dst + 8)  = o[1];
            *(half8*)(dst + 16) = o[2];
        }
    } else {
        // ================= B1: xg1t(c1) = h0(c1) @ Wih1^T + bih1 (+bhh1 r,z) =================
        const int c1 = k - 1;
        if (c1 < 0 || c1 >= NCH) return;
        const _Float16* hof = (c1 & 1) ? hout1 : hout0;
        _Float16* xg1 = (c1 & 1) ? xg1b : xg1a;
        const int fb = bid - 96;                  // 0..127
        const int sub = tid >> 8;
        const int t = tid & 255;
        const int wv = t >> 6, lane = t & 63;
        const int q = lane >> 4, lm = lane & 15;
        const int asel = (lane >> 3) & 1;
        const int cidx = (lane >> 4) * 8 + (lane & 7);

        float bias[12];
#pragma unroll
        for (int j = 0; j < 12; j++) {
            int n = (wv * 12 + j) * 16 + lm;
            bias[j] = bih1[n] + (n < 512 ? bhh1[n] : 0.f);
        }
        const int t16 = (fb * 2 + sub) * 2;       // 2 m-tiles per 256-half
        f32x4 acc[2][12] = {};
#pragma unroll
        for (int kt = 0; kt < 8; kt++) {
            half8 af[2], bf[12];
#pragma unroll
            for (int i = 0; i < 2; i++) {
                int tt = t16 + i, s = tt >> 4, bt = tt & 15;
                af[i] = *(const half8*)(hof +
                    (((size_t)(s * 32 + bt * 2 + asel) * 8 + kt) * 32 + cidx) * 8);
            }
#pragma unroll
            for (int j = 0; j < 12; j++)
                bf[j] = *(const half8*)(Wi1frag + (size_t)((kt * 48 + wv * 12 + j) * 64 + lane) * 8);
#pragma unroll
            for (int i = 0; i < 2; i++)
#pragma unroll
                for (int j = 0; j < 12; j++)
                    acc[i][j] = __builtin_amdgcn_mfma_f32_16x16x32_f16(af[i], bf[j], acc[i][j], 0, 0, 0);
        }
#pragma unroll
        for (int i = 0; i < 2; i++) {
            int tt = t16 + i, s = tt >> 4, bt = tt & 15;
            int blk = bt * 2 + (q >> 1), qc2 = q & 1;
#pragma unroll
            for (int j = 0; j < 12; j++) {
                int n = (wv * 12 + j) * 16 + lm;
                int g3 = n >> 8, nn = n & 255;
                int wc = nn >> 5, tp = (nn >> 4) & 1, lmc = nn & 15;
                half4_t v;
#pragma unroll
                for (int r = 0; r < 4; r++) v[r] = (_Float16)(acc[i][j][r] + bias[j]);
                *(half4_t*)(xg1 + (((size_t)(s * 32 + blk) * 8 + wc) * 32 + qc2 * 16 + lmc) * 24
                                 + g3 * 8 + tp * 4) = v;
            }
        }
    }
}

extern "C" void kernel_launch(void* const* d_in, const int* in_sizes, int n_in,
                              void* d_out, int out_size, void* d_ws, size_t ws_size,
                              hipStream_t stream) {
    const float* x    = (const float*)d_in[0];
    const float* meta = (const float*)d_in[1];
    const float* Wih0 = (const float*)d_in[2];
    const float* Whh0 = (const float*)d_in[3];
    const float* bih0 = (const float*)d_in[4];
    const float* bhh0 = (const float*)d_in[5];
    const float* Wih1 = (const float*)d_in[6];
    const float* Whh1 = (const float*)d_in[7];
    const float* bih1 = (const float*)d_in[8];
    const float* bhh1 = (const float*)d_in[9];
    const float* fcW  = (const float*)d_in[10];
    const float* fcb  = (const float*)d_in[11];
    float* out = (float*)d_out;

    char* ws = (char*)d_ws;
    _Float16* Wfrag0  = (_Float16*)(ws + 0);
    _Float16* Wfrag1  = (_Float16*)(ws + 393216);
    _Float16* Wi1frag = (_Float16*)(ws + 786432);
    float*    hst0    = (float*)(ws + 1179648);
    float*    hst1    = (float*)(ws + 1703936);
    _Float16* hout0   = (_Float16*)(ws + 2228224);
    _Float16* hout1   = (_Float16*)(ws + 6422528);
    _Float16* xg0a    = (_Float16*)(ws + 10616832);
    _Float16* xg0b    = (_Float16*)(ws + 23199744);
    _Float16* xg1a    = (_Float16*)(ws + 35782656);
    _Float16* xg1b    = (_Float16*)(ws + 48365568);

    prep_kernel<<<288, 256, 0, stream>>>(Whh0, Whh1, Wih1, Wfrag0, Wfrag1, Wi1frag);

    for (int k = -1; k <= NCH + 1; k++) {
        mega_kernel<<<224, 512, 0, stream>>>(
            x, meta, Wih0, bih0, bhh0, Wfrag0, Wfrag1, Wi1frag, bih1, bhh1,
            hst0, hst1, hout0, hout1, xg0a, xg0b, xg1a, xg1b, fcW, fcb, out, k);
    }
}